// Round 6
// baseline (466.824 us; speedup 1.0000x reference)
//
#include <hip/hip_runtime.h>

#define N_NODES 100000
#define N_EDGES 3200000
#define IN_F    256
#define OUT_F   256
#define CLAMP_V 10.0f
#define NRW     13          // rows per wave in spmm_phased
#define NPHASE  4
#define PCHUNK  25000       // cols per phase slice (12.8 MB bf16 support)

typedef __attribute__((ext_vector_type(8))) short bf16x8;
typedef __attribute__((ext_vector_type(4))) float f32x4;

__device__ __forceinline__ float clampf(float v) {
    return fminf(fmaxf(v, -CLAMP_V), CLAMP_V);
}
// RNE float -> bf16 (inputs clamped/finite)
__device__ __forceinline__ unsigned f2bf(float f) {
    unsigned u = __float_as_uint(f);
    u += 0x7fffu + ((u >> 16) & 1u);
    return u >> 16;
}
// packed 2x f32 -> 2x bf16 in one u32
__device__ __forceinline__ unsigned cvt_pk_bf16(float lo, float hi) {
    unsigned r;
    asm("v_cvt_pk_bf16_f32 %0, %1, %2" : "=v"(r) : "v"(lo), "v"(hi));
    return r;
}
__device__ __forceinline__ float bflo(unsigned w) { return __uint_as_float(w << 16); }
__device__ __forceinline__ float bfhi(unsigned w) { return __uint_as_float(w & 0xffff0000u); }

// ---------------------------------------------------------------------------
// Kernel 0: W fp32 [K][N] -> bf16 pre-swizzled:
// element (k,n) at ushort index  n*256 + ((k>>3) ^ (n&7))*8 + (k&7).
// ---------------------------------------------------------------------------
__global__ __launch_bounds__(256) void convert_w(
    const float* __restrict__ w, unsigned short* __restrict__ wt) {
    int i = blockIdx.x * 256 + threadIdx.x;   // 65536
    int k = i & 255, n = i >> 8;
    float v = w[(size_t)k * OUT_F + n];
    int dst = n * 256 + (((k >> 3) ^ (n & 7)) << 3) + (k & 7);
    wt[dst] = (unsigned short)f2bf(v);
}

// ---------------------------------------------------------------------------
// Kernel 1: CSR row_ptr from sorted adj_rows (binary search per row).
// ---------------------------------------------------------------------------
__global__ __launch_bounds__(256) void build_row_ptr(
    const int* __restrict__ rows, int* __restrict__ row_ptr) {
    int r = blockIdx.x * blockDim.x + threadIdx.x;
    if (r > N_NODES) return;
    int lo = 0, hi = N_EDGES;
    while (lo < hi) {
        int mid = (lo + hi) >> 1;
        if (rows[mid] < r) lo = mid + 1; else hi = mid;
    }
    row_ptr[r] = lo;
}

// ---------------------------------------------------------------------------
// Kernel 2: per-row counting-sort of edges into NPHASE col-buckets.
// Output: packed[e] = (col << 15) | round(val * 32767)   (val in [0,1))
//         pp5[row*5 + p] = start of bucket p; pp5[row*5+4] = row end.
// One wave per row; ballot-based stable partition, 64-edge chunks.
// ---------------------------------------------------------------------------
__global__ __launch_bounds__(256) void sort_edges(
    const int* __restrict__ row_ptr, const int* __restrict__ cols,
    const float* __restrict__ vals, unsigned* __restrict__ packed,
    int* __restrict__ pp5) {
    const int wid  = threadIdx.x >> 6;
    const int lane = threadIdx.x & 63;
    const int row  = blockIdx.x * 4 + wid;
    if (row >= N_NODES) return;
    const int e0 = row_ptr[row], e1 = row_ptr[row + 1];
    const unsigned long long lt = (1ull << lane) - 1ull;

    int cnt0 = 0, cnt1 = 0, cnt2 = 0;
    for (int cb = e0; cb < e1; cb += 64) {
        int  idx   = cb + lane;
        bool valid = idx < e1;
        int  col   = valid ? cols[idx] : 0;
        int  b = (col >= PCHUNK) + (col >= 2 * PCHUNK) + (col >= 3 * PCHUNK);
        cnt0 += __popcll(__ballot(valid && b == 0));
        cnt1 += __popcll(__ballot(valid && b == 1));
        cnt2 += __popcll(__ballot(valid && b == 2));
    }
    int s0 = e0, s1 = s0 + cnt0, s2 = s1 + cnt1, s3 = s2 + cnt2;
    if (lane == 0) {
        pp5[row * 5 + 0] = s0; pp5[row * 5 + 1] = s1; pp5[row * 5 + 2] = s2;
        pp5[row * 5 + 3] = s3; pp5[row * 5 + 4] = e1;
    }
    int c0 = s0, c1 = s1, c2 = s2, c3 = s3;
    for (int cb = e0; cb < e1; cb += 64) {
        int   idx   = cb + lane;
        bool  valid = idx < e1;
        int   col   = valid ? cols[idx] : 0;
        float v     = valid ? vals[idx] : 0.f;
        int   b = (col >= PCHUNK) + (col >= 2 * PCHUNK) + (col >= 3 * PCHUNK);
        unsigned pk = ((unsigned)col << 15) | (unsigned)(v * 32767.f + 0.5f);
        unsigned long long m;
        m = __ballot(valid && b == 0); if (valid && b == 0) packed[c0 + __popcll(m & lt)] = pk; c0 += __popcll(m);
        m = __ballot(valid && b == 1); if (valid && b == 1) packed[c1 + __popcll(m & lt)] = pk; c1 += __popcll(m);
        m = __ballot(valid && b == 2); if (valid && b == 2) packed[c2 + __popcll(m & lt)] = pk; c2 += __popcll(m);
        m = __ballot(valid && b == 3); if (valid && b == 3) packed[c3 + __popcll(m & lt)] = pk; c3 += __popcll(m);
    }
}

// ---------------------------------------------------------------------------
// Kernel 3: support(bf16) = clip(clip(x) @ W) via mfma_f32_16x16x32_bf16.
// 512 threads / 8 waves; block = 128 rows x 256 cols. W in LDS (128 KB,
// pre-swizzled); A loaded straight to registers (no K-loop barriers).
// ---------------------------------------------------------------------------
__global__ __launch_bounds__(512) void gemm_mfma(
    const float* __restrict__ x, const unsigned short* __restrict__ wt,
    unsigned short* __restrict__ support) {
    __shared__ uint4 wlds[8192];    // 128 KB

    const int t    = threadIdx.x;
    const int lane = t & 63;
    const int w    = t >> 6;
    const int wr   = w >> 2;
    const int wc   = w & 3;
    const int l15  = lane & 15;
    const int l4   = lane >> 4;
    const int blockRow = blockIdx.x * 128;

    {
        const uint4* g = (const uint4*)wt;
        #pragma unroll
        for (int i = 0; i < 16; ++i)
            wlds[i * 512 + t] = g[i * 512 + t];
    }

    const float* aptr[4];
    #pragma unroll
    for (int m = 0; m < 4; ++m) {
        int r = blockRow + wr * 64 + m * 16 + l15;
        aptr[m] = x + (size_t)(r < N_NODES ? r : N_NODES - 1) * IN_F + l4 * 8;
    }

    f32x4 acc[4][4];
    #pragma unroll
    for (int m = 0; m < 4; ++m)
        #pragma unroll
        for (int n = 0; n < 4; ++n)
            acc[m][n] = (f32x4)0.f;

    __syncthreads();    // W ready

    #pragma unroll
    for (int s = 0; s < 8; ++s) {
        bf16x8 a[4], b[4];
        #pragma unroll
        for (int m = 0; m < 4; ++m) {
            float4 u0 = *(const float4*)(aptr[m] + s * 32);
            float4 u1 = *(const float4*)(aptr[m] + s * 32 + 4);
            union { unsigned u[4]; bf16x8 v; } pk;
            pk.u[0] = cvt_pk_bf16(clampf(u0.x), clampf(u0.y));
            pk.u[1] = cvt_pk_bf16(clampf(u0.z), clampf(u0.w));
            pk.u[2] = cvt_pk_bf16(clampf(u1.x), clampf(u1.y));
            pk.u[3] = cvt_pk_bf16(clampf(u1.z), clampf(u1.w));
            a[m] = pk.v;
        }
        #pragma unroll
        for (int n = 0; n < 4; ++n) {
            int ncol  = wc * 64 + n * 16 + l15;
            int chunk = ncol * 32 + ((s * 4 + l4) ^ (ncol & 7));
            b[n] = *(const bf16x8*)&wlds[chunk];
        }
        #pragma unroll
        for (int m = 0; m < 4; ++m)
            #pragma unroll
            for (int n = 0; n < 4; ++n)
                acc[m][n] = __builtin_amdgcn_mfma_f32_16x16x32_bf16(
                    a[m], b[n], acc[m][n], 0, 0, 0);
    }

    // epilogue: acc -> LDS (bf16, swizzled) -> coalesced uint4 stores
    __syncthreads();
    {
        char* sl = (char*)wlds;     // 128 x 512 B
        #pragma unroll
        for (int m = 0; m < 4; ++m) {
            #pragma unroll
            for (int n = 0; n < 4; ++n) {
                int col2 = (wc * 64 + n * 16 + l15) * 2;
                #pragma unroll
                for (int r = 0; r < 4; ++r) {
                    int row = wr * 64 + m * 16 + l4 * 4 + r;
                    int off = row * 512 + (col2 ^ (((row >> 2) & 3) << 4));
                    *(unsigned short*)(sl + off) = (unsigned short)f2bf(clampf(acc[m][n][r]));
                }
            }
        }
    }
    __syncthreads();
    {
        const uint4* sl4 = (const uint4*)wlds;
        #pragma unroll
        for (int i = 0; i < 8; ++i) {
            int c    = i * 512 + t;
            int row  = c >> 5;
            int q    = c & 31;
            int grow = blockRow + row;
            if (grow < N_NODES) {
                uint4 v = sl4[row * 32 + (q ^ ((row >> 2) & 3))];
                *(uint4*)(support + (size_t)grow * OUT_F + q * 8) = v;
            }
        }
    }
}

// ---------------------------------------------------------------------------
// Kernel 4: phased SpMM. Wave owns NRW rows (acc in registers, statically
// unrolled); outer loop over NPHASE col-slices so concurrent gathers hit a
// 12.8 MB L2/L3-resident slice of support. Lane owns 4 feats (8 B uint2).
// ---------------------------------------------------------------------------
__global__ __launch_bounds__(256, 4) void spmm_phased(
    const unsigned short* __restrict__ support, const int* __restrict__ pp5,
    const unsigned* __restrict__ packed, const float* __restrict__ bias,
    float* __restrict__ out) {
    const int wid  = threadIdx.x >> 6;
    const int lane = threadIdx.x & 63;
    const int wave = blockIdx.x * 4 + wid;
    const int rowBase = wave * NRW;
    if (rowBase >= N_NODES) return;

    const uint2* sup2 = (const uint2*)support;   // 64 x 8B chunks per node
    float acc[NRW][4];
    #pragma unroll
    for (int ri = 0; ri < NRW; ++ri) {
        acc[ri][0] = 0.f; acc[ri][1] = 0.f; acc[ri][2] = 0.f; acc[ri][3] = 0.f;
    }

    for (int p = 0; p < NPHASE; ++p) {
        #pragma unroll
        for (int ri = 0; ri < NRW; ++ri) {
            int row = rowBase + ri;
            if (row < N_NODES) {
                int ea = pp5[row * 5 + p];
                int eb = pp5[row * 5 + p + 1];
                int e  = ea;
                for (; e + 2 <= eb; e += 2) {
                    unsigned k0 = packed[e], k1 = packed[e + 1];
                    float v0 = (float)(k0 & 32767u) * (1.f / 32767.f);
                    float v1 = (float)(k1 & 32767u) * (1.f / 32767.f);
                    uint2 g0 = sup2[(size_t)(k0 >> 15) * 64 + lane];
                    uint2 g1 = sup2[(size_t)(k1 >> 15) * 64 + lane];
                    acc[ri][0] += v0 * bflo(g0.x); acc[ri][1] += v0 * bfhi(g0.x);
                    acc[ri][2] += v0 * bflo(g0.y); acc[ri][3] += v0 * bfhi(g0.y);
                    acc[ri][0] += v1 * bflo(g1.x); acc[ri][1] += v1 * bfhi(g1.x);
                    acc[ri][2] += v1 * bflo(g1.y); acc[ri][3] += v1 * bfhi(g1.y);
                }
                if (e < eb) {
                    unsigned k0 = packed[e];
                    float v0 = (float)(k0 & 32767u) * (1.f / 32767.f);
                    uint2 g0 = sup2[(size_t)(k0 >> 15) * 64 + lane];
                    acc[ri][0] += v0 * bflo(g0.x); acc[ri][1] += v0 * bfhi(g0.x);
                    acc[ri][2] += v0 * bflo(g0.y); acc[ri][3] += v0 * bfhi(g0.y);
                }
            }
        }
    }

    const float4 b4 = ((const float4*)bias)[lane];
    #pragma unroll
    for (int ri = 0; ri < NRW; ++ri) {
        int row = rowBase + ri;
        if (row < N_NODES) {
            f32x4 o;
            o.x = fminf(fmaxf(clampf(acc[ri][0]) + b4.x, 0.f), CLAMP_V);
            o.y = fminf(fmaxf(clampf(acc[ri][1]) + b4.y, 0.f), CLAMP_V);
            o.z = fminf(fmaxf(clampf(acc[ri][2]) + b4.z, 0.f), CLAMP_V);
            o.w = fminf(fmaxf(clampf(acc[ri][3]) + b4.w, 0.f), CLAMP_V);
            __builtin_nontemporal_store(o, (f32x4*)out + (size_t)row * 64 + lane);
        }
    }
}

// ---------------------------------------------------------------------------
extern "C" void kernel_launch(void* const* d_in, const int* in_sizes, int n_in,
                              void* d_out, int out_size, void* d_ws, size_t ws_size,
                              hipStream_t stream) {
    const float* x        = (const float*)d_in[0];
    const int*   adj_rows = (const int*)d_in[1];
    const int*   adj_cols = (const int*)d_in[2];
    const float* adj_vals = (const float*)d_in[3];
    const float* weight   = (const float*)d_in[4];
    const float* bias     = (const float*)d_in[5];
    float*       out      = (float*)d_out;

    // ws: support 51.2MB | packed 12.8MB | pp5 2MB | row_ptr 0.4MB | wt 128KB
    char* ws = (char*)d_ws;
    unsigned short* support = (unsigned short*)ws;                  // 51,200,000
    unsigned*       packed  = (unsigned*)(ws + 51200000);           // 12,800,000
    int*            pp5     = (int*)(ws + 64000000);                //  2,000,000
    int*            row_ptr = (int*)(ws + 66000000);                //    400,004
    unsigned short* wt      = (unsigned short*)(ws + 66400032);     //    131,072

    convert_w<<<256, 256, 0, stream>>>(weight, wt);
    build_row_ptr<<<(N_NODES + 1 + 255) / 256, 256, 0, stream>>>(adj_rows, row_ptr);
    sort_edges<<<(N_NODES + 3) / 4, 256, 0, stream>>>(row_ptr, adj_cols, adj_vals,
                                                      packed, pp5);
    gemm_mfma<<<(N_NODES + 127) / 128, 512, 0, stream>>>(x, wt, support);

    const int nwaves  = (N_NODES + NRW - 1) / NRW;      // 7693
    const int nblocks = (nwaves + 3) / 4;               // 1924
    spmm_phased<<<nblocks, 256, 0, stream>>>(support, pp5, packed, bias, out);
}

// Round 7
// 238.671 us; speedup vs baseline: 1.9559x; 1.9559x over previous
//
#include <hip/hip_runtime.h>

#define N_NODES 100000
#define N_EDGES 3200000
#define IN_F    256
#define OUT_F   256
#define CLAMP_V 10.0f

typedef __attribute__((ext_vector_type(8))) short bf16x8;
typedef __attribute__((ext_vector_type(4))) float f32x4;

__device__ __forceinline__ float clampf(float v) {
    return fminf(fmaxf(v, -CLAMP_V), CLAMP_V);
}
// RNE float -> bf16 (inputs clamped/finite)
__device__ __forceinline__ unsigned f2bf(float f) {
    unsigned u = __float_as_uint(f);
    u += 0x7fffu + ((u >> 16) & 1u);
    return u >> 16;
}
// packed 2x f32 -> 2x bf16 in one u32
__device__ __forceinline__ unsigned cvt_pk_bf16(float lo, float hi) {
    unsigned r;
    asm("v_cvt_pk_bf16_f32 %0, %1, %2" : "=v"(r) : "v"(lo), "v"(hi));
    return r;
}
__device__ __forceinline__ float bflo(unsigned w) { return __uint_as_float(w << 16); }
__device__ __forceinline__ float bfhi(unsigned w) { return __uint_as_float(w & 0xffff0000u); }

// ---------------------------------------------------------------------------
// Kernel 0: W fp32 [K][N] -> bf16 pre-swizzled:
// element (k,n) at ushort index  n*256 + ((k>>3) ^ (n&7))*8 + (k&7).
// ---------------------------------------------------------------------------
__global__ __launch_bounds__(256) void convert_w(
    const float* __restrict__ w, unsigned short* __restrict__ wt) {
    int i = blockIdx.x * 256 + threadIdx.x;   // 65536
    int k = i & 255, n = i >> 8;
    float v = w[(size_t)k * OUT_F + n];
    int dst = n * 256 + (((k >> 3) ^ (n & 7)) << 3) + (k & 7);
    wt[dst] = (unsigned short)f2bf(v);
}

// ---------------------------------------------------------------------------
// Kernel 1: CSR row_ptr from sorted adj_rows (binary search per row).
// ---------------------------------------------------------------------------
__global__ __launch_bounds__(256) void build_row_ptr(
    const int* __restrict__ rows, int* __restrict__ row_ptr) {
    int r = blockIdx.x * blockDim.x + threadIdx.x;
    if (r > N_NODES) return;
    int lo = 0, hi = N_EDGES;
    while (lo < hi) {
        int mid = (lo + hi) >> 1;
        if (rows[mid] < r) lo = mid + 1; else hi = mid;
    }
    row_ptr[r] = lo;
}

// ---------------------------------------------------------------------------
// Kernel 2: support_bf16 = clip(clip(x) @ W) via mfma_f32_16x16x32_bf16.
// 1024 threads / 16 waves; block = 256 rows x 256 cols (full N).
// W fully in LDS (128 KB, pre-swizzled). A loaded straight to registers
// (no K-loop barriers). Wave (wr,wc) in 4x4 grid owns 64x64 (4x4 frags).
// Output staged to d_out (bf16) for the quant8 kernel.
// ---------------------------------------------------------------------------
__global__ __launch_bounds__(1024) void gemm_mfma(
    const float* __restrict__ x, const unsigned short* __restrict__ wt,
    unsigned short* __restrict__ support) {
    __shared__ uint4 wlds[8192];    // 128 KB

    const int t    = threadIdx.x;
    const int lane = t & 63;
    const int w    = t >> 6;        // 0..15
    const int wr   = w >> 2;        // 0..3
    const int wc   = w & 3;         // 0..3
    const int l15  = lane & 15;
    const int l4   = lane >> 4;     // 0..3
    const int blockRow = blockIdx.x * 256;

    {
        const uint4* g = (const uint4*)wt;
        #pragma unroll
        for (int i = 0; i < 8; ++i)
            wlds[i * 1024 + t] = g[i * 1024 + t];
    }

    const float* aptr[4];
    #pragma unroll
    for (int m = 0; m < 4; ++m) {
        int r = blockRow + wr * 64 + m * 16 + l15;
        aptr[m] = x + (size_t)(r < N_NODES ? r : N_NODES - 1) * IN_F + l4 * 8;
    }

    f32x4 acc[4][4];
    #pragma unroll
    for (int m = 0; m < 4; ++m)
        #pragma unroll
        for (int n = 0; n < 4; ++n)
            acc[m][n] = (f32x4)0.f;

    __syncthreads();    // W ready

    #pragma unroll
    for (int s = 0; s < 8; ++s) {
        bf16x8 a[4], b[4];
        #pragma unroll
        for (int m = 0; m < 4; ++m) {
            float4 u0 = *(const float4*)(aptr[m] + s * 32);
            float4 u1 = *(const float4*)(aptr[m] + s * 32 + 4);
            union { unsigned u[4]; bf16x8 v; } pk;
            pk.u[0] = cvt_pk_bf16(clampf(u0.x), clampf(u0.y));
            pk.u[1] = cvt_pk_bf16(clampf(u0.z), clampf(u0.w));
            pk.u[2] = cvt_pk_bf16(clampf(u1.x), clampf(u1.y));
            pk.u[3] = cvt_pk_bf16(clampf(u1.z), clampf(u1.w));
            a[m] = pk.v;
        }
        #pragma unroll
        for (int n = 0; n < 4; ++n) {
            int ncol  = wc * 64 + n * 16 + l15;
            int chunk = ncol * 32 + ((s * 4 + l4) ^ (ncol & 7));
            b[n] = *(const bf16x8*)&wlds[chunk];
        }
        #pragma unroll
        for (int m = 0; m < 4; ++m)
            #pragma unroll
            for (int n = 0; n < 4; ++n)
                acc[m][n] = __builtin_amdgcn_mfma_f32_16x16x32_bf16(
                    a[m], b[n], acc[m][n], 0, 0, 0);
    }

    // epilogue: acc -> LDS (bf16, chunk-swizzled) -> coalesced uint4 stores
    __syncthreads();
    {
        char* sl = (char*)wlds;     // 256 rows x 512 B = 128 KB
        #pragma unroll
        for (int m = 0; m < 4; ++m) {
            #pragma unroll
            for (int n = 0; n < 4; ++n) {
                int col2 = (wc * 64 + n * 16 + l15) * 2;
                #pragma unroll
                for (int r = 0; r < 4; ++r) {
                    int row = wr * 64 + m * 16 + l4 * 4 + r;
                    int off = row * 512 + (col2 ^ (((row >> 2) & 3) << 4));
                    *(unsigned short*)(sl + off) = (unsigned short)f2bf(clampf(acc[m][n][r]));
                }
            }
        }
    }
    __syncthreads();
    {
        const uint4* sl4 = (const uint4*)wlds;
        #pragma unroll
        for (int i = 0; i < 8; ++i) {
            int c    = i * 1024 + t;        // 0..8191 16B chunks
            int row  = c >> 5;              // 0..255
            int q    = c & 31;
            int grow = blockRow + row;
            if (grow < N_NODES) {
                uint4 v = sl4[row * 32 + (q ^ ((row >> 2) & 3))];
                *(uint4*)(support + (size_t)grow * OUT_F + q * 8) = v;
            }
        }
    }
}

// ---------------------------------------------------------------------------
// Kernel 3: quantize support bf16 -> int8 (offset-binary) + per-row scale.
// One wave per row: lane owns 4 feats (8 B), shfl-max for rowmax,
// store b = rint(v*127/rowmax)+128 packed 4/uint, scale[row] = rowmax/127.
// ---------------------------------------------------------------------------
__global__ __launch_bounds__(256) void quant8(
    const unsigned short* __restrict__ supb, unsigned* __restrict__ sup8,
    float* __restrict__ scales) {
    const int wid  = threadIdx.x >> 6;
    const int lane = threadIdx.x & 63;
    const int row  = blockIdx.x * 4 + wid;
    if (row >= N_NODES) return;

    uint2 g = ((const uint2*)supb)[(size_t)row * 64 + lane];
    float a0 = bflo(g.x), a1 = bfhi(g.x), a2 = bflo(g.y), a3 = bfhi(g.y);
    float m = fmaxf(fmaxf(fabsf(a0), fabsf(a1)), fmaxf(fabsf(a2), fabsf(a3)));
    #pragma unroll
    for (int s = 1; s < 64; s <<= 1)
        m = fmaxf(m, __shfl_xor(m, s));

    float inv = 127.f / fmaxf(m, 1e-30f);
    unsigned b0 = (unsigned)(int)rintf(a0 * inv) + 128u;
    unsigned b1 = (unsigned)(int)rintf(a1 * inv) + 128u;
    unsigned b2 = (unsigned)(int)rintf(a2 * inv) + 128u;
    unsigned b3 = (unsigned)(int)rintf(a3 * inv) + 128u;
    sup8[(size_t)row * 64 + lane] = b0 | (b1 << 8) | (b2 << 16) | (b3 << 24);
    if (lane == 0) scales[row] = m * (1.f / 127.f);
}

// ---------------------------------------------------------------------------
// Kernel 4: out[r] = clip(relu(clip(sum val*support[c]) + bias)).
// One wave per row; lanes 0-31 even edge, 32-63 odd edge; 8 B (8 int8
// feats) per lane per edge. Dequant folded: acc += (val*scale)*ubyte with
// a single -128*S correction at the end. fp32 accumulate.
// ---------------------------------------------------------------------------
#define FMAQ(g, vs)                                                       \
    S += (vs);                                                            \
    acc[0] += (vs) * (float)((g).x & 0xffu);                              \
    acc[1] += (vs) * (float)(((g).x >> 8) & 0xffu);                       \
    acc[2] += (vs) * (float)(((g).x >> 16) & 0xffu);                      \
    acc[3] += (vs) * (float)((g).x >> 24);                                \
    acc[4] += (vs) * (float)((g).y & 0xffu);                              \
    acc[5] += (vs) * (float)(((g).y >> 8) & 0xffu);                       \
    acc[6] += (vs) * (float)(((g).y >> 16) & 0xffu);                      \
    acc[7] += (vs) * (float)((g).y >> 24);

__global__ __launch_bounds__(256) void spmm_out(
    const unsigned* __restrict__ sup8, const float* __restrict__ scales,
    const int* __restrict__ row_ptr, const int* __restrict__ cols,
    const float* __restrict__ vals, const float* __restrict__ bias,
    float* __restrict__ out) {
    const int wid  = threadIdx.x >> 6;
    const int lane = threadIdx.x & 63;
    const int row  = blockIdx.x * 4 + wid;
    if (row >= N_NODES) return;

    const int e0   = row_ptr[row];
    const int e1   = row_ptr[row + 1];
    const int half = lane >> 5;       // 0: even edge, 1: odd edge
    const int c32  = lane & 31;       // 8B chunk within node row (32 chunks)

    const uint2* sup2 = (const uint2*)sup8;
    float acc[8] = {0.f,0.f,0.f,0.f,0.f,0.f,0.f,0.f};
    float S = 0.f;

    int e = e0;
    for (; e + 4 <= e1; e += 4) {
        int   ea = e + half, eb = ea + 2;
        int   ca = cols[ea], cb = cols[eb];
        float va = vals[ea], vb = vals[eb];
        float vsa = va * scales[ca], vsb = vb * scales[cb];
        uint2 ga = sup2[(size_t)ca * 32 + c32];
        uint2 gb = sup2[(size_t)cb * 32 + c32];
        FMAQ(ga, vsa); FMAQ(gb, vsb);
    }
    for (; e < e1; e += 2) {
        int   ea = e + half;
        bool  ok = ea < e1;
        int   ca = cols[ok ? ea : e];
        float va = ok ? vals[ea] : 0.f;
        float vsa = va * scales[ca];
        uint2 ga = sup2[(size_t)ca * 32 + c32];
        FMAQ(ga, vsa);
    }

    // offset-binary correction: true dequant = (b - 128) * scale
    S *= 128.f;
    #pragma unroll
    for (int j = 0; j < 8; ++j)
        acc[j] -= S;

    #pragma unroll
    for (int j = 0; j < 8; ++j)
        acc[j] += __shfl_xor(acc[j], 32);

    const float4 b4 = ((const float4*)bias)[c32 * 2 + half];
    f32x4 o;
    o.x = fminf(fmaxf(clampf(acc[half * 4 + 0]) + b4.x, 0.f), CLAMP_V);
    o.y = fminf(fmaxf(clampf(acc[half * 4 + 1]) + b4.y, 0.f), CLAMP_V);
    o.z = fminf(fmaxf(clampf(acc[half * 4 + 2]) + b4.z, 0.f), CLAMP_V);
    o.w = fminf(fmaxf(clampf(acc[half * 4 + 3]) + b4.w, 0.f), CLAMP_V);
    __builtin_nontemporal_store(o, (f32x4*)(out + (size_t)row * OUT_F + c32 * 8 + half * 4));
}

// ---------------------------------------------------------------------------
extern "C" void kernel_launch(void* const* d_in, const int* in_sizes, int n_in,
                              void* d_out, int out_size, void* d_ws, size_t ws_size,
                              hipStream_t stream) {
    const float* x        = (const float*)d_in[0];
    const int*   adj_rows = (const int*)d_in[1];
    const int*   adj_cols = (const int*)d_in[2];
    const float* adj_vals = (const float*)d_in[3];
    const float* weight   = (const float*)d_in[4];
    const float* bias     = (const float*)d_in[5];
    float*       out      = (float*)d_out;

    // bf16 support STAGED IN d_out (51.2 MB of its 102.4 MB); quant8 consumes
    // it before spmm_out overwrites d_out with the final result.
    unsigned short* supb = (unsigned short*)d_out;

    // ws: sup8 25.6MB | scales 400KB | row_ptr 400KB | wt 128KB  (~26.5 MB)
    char* ws = (char*)d_ws;
    unsigned*       sup8    = (unsigned*)ws;                        // 25,600,000
    float*          scales  = (float*)(ws + 25600000);              //    400,000
    int*            row_ptr = (int*)(ws + 26000000);                //    400,004
    unsigned short* wt      = (unsigned short*)(ws + 26400064);     //    131,072

    convert_w<<<256, 256, 0, stream>>>(weight, wt);
    build_row_ptr<<<(N_NODES + 1 + 255) / 256, 256, 0, stream>>>(adj_rows, row_ptr);
    gemm_mfma<<<(N_NODES + 255) / 256, 1024, 0, stream>>>(x, wt, supb);
    quant8<<<(N_NODES + 3) / 4, 256, 0, stream>>>(supb, sup8, scales);
    spmm_out<<<(N_NODES + 3) / 4, 256, 0, stream>>>(sup8, scales, row_ptr,
                                                    adj_cols, adj_vals, bias, out);
}

// Round 8
// 212.447 us; speedup vs baseline: 2.1974x; 1.1234x over previous
//
#include <hip/hip_runtime.h>

#define N_NODES 100000
#define N_EDGES 3200000
#define IN_F    256
#define OUT_F   256
#define CLAMP_V 10.0f

typedef __attribute__((ext_vector_type(8))) short bf16x8;
typedef __attribute__((ext_vector_type(4))) float f32x4;

__device__ __forceinline__ float clampf(float v) {
    return fminf(fmaxf(v, -CLAMP_V), CLAMP_V);
}
// RNE float -> bf16 (inputs clamped/finite)
__device__ __forceinline__ unsigned f2bf(float f) {
    unsigned u = __float_as_uint(f);
    u += 0x7fffu + ((u >> 16) & 1u);
    return u >> 16;
}
// packed 2x f32 -> 2x bf16 in one u32
__device__ __forceinline__ unsigned cvt_pk_bf16(float lo, float hi) {
    unsigned r;
    asm("v_cvt_pk_bf16_f32 %0, %1, %2" : "=v"(r) : "v"(lo), "v"(hi));
    return r;
}
__device__ __forceinline__ float bflo(unsigned w) { return __uint_as_float(w << 16); }
__device__ __forceinline__ float bfhi(unsigned w) { return __uint_as_float(w & 0xffff0000u); }

// ---------------------------------------------------------------------------
// Kernel 0: W fp32 [K][N] -> bf16 pre-swizzled:
// element (k,n) at ushort index  n*256 + ((k>>3) ^ (n&7))*8 + (k&7).
// ---------------------------------------------------------------------------
__global__ __launch_bounds__(256) void convert_w(
    const float* __restrict__ w, unsigned short* __restrict__ wt) {
    int i = blockIdx.x * 256 + threadIdx.x;   // 65536
    int k = i & 255, n = i >> 8;
    float v = w[(size_t)k * OUT_F + n];
    int dst = n * 256 + (((k >> 3) ^ (n & 7)) << 3) + (k & 7);
    wt[dst] = (unsigned short)f2bf(v);
}

// ---------------------------------------------------------------------------
// Kernel 1: CSR row_ptr from sorted adj_rows (binary search per row).
// ---------------------------------------------------------------------------
__global__ __launch_bounds__(256) void build_row_ptr(
    const int* __restrict__ rows, int* __restrict__ row_ptr) {
    int r = blockIdx.x * blockDim.x + threadIdx.x;
    if (r > N_NODES) return;
    int lo = 0, hi = N_EDGES;
    while (lo < hi) {
        int mid = (lo + hi) >> 1;
        if (rows[mid] < r) lo = mid + 1; else hi = mid;
    }
    row_ptr[r] = lo;
}

// ---------------------------------------------------------------------------
// Kernel 2: fused GEMM + int8 quantization.
// support = clip(clip(x) @ W) -> per-row int8 (offset-binary) + scale.
// 1024 threads / 16 waves; block = 256 rows x 256 cols (full N), so each
// block owns complete node rows -> rowmax computable in the epilogue.
// W fully in LDS (128 KB, pre-swizzled); A loaded straight to registers.
// Epilogue: acc -> LDS bf16 (swizzled) -> rowmax (4 thr/row + shfl) ->
// quantize in-register -> coalesced int8 stores. No separate quant pass.
// ---------------------------------------------------------------------------
__global__ __launch_bounds__(1024) void gemm_mfma(
    const float* __restrict__ x, const unsigned short* __restrict__ wt,
    unsigned* __restrict__ sup8, float* __restrict__ scales) {
    __shared__ uint4 wlds[8192];    // 128 KB

    const int t    = threadIdx.x;
    const int lane = t & 63;
    const int w    = t >> 6;        // 0..15
    const int wr   = w >> 2;        // 0..3
    const int wc   = w & 3;         // 0..3
    const int l15  = lane & 15;
    const int l4   = lane >> 4;     // 0..3
    const int blockRow = blockIdx.x * 256;

    {
        const uint4* g = (const uint4*)wt;
        #pragma unroll
        for (int i = 0; i < 8; ++i)
            wlds[i * 1024 + t] = g[i * 1024 + t];
    }

    const float* aptr[4];
    #pragma unroll
    for (int m = 0; m < 4; ++m) {
        int r = blockRow + wr * 64 + m * 16 + l15;
        aptr[m] = x + (size_t)(r < N_NODES ? r : N_NODES - 1) * IN_F + l4 * 8;
    }

    f32x4 acc[4][4];
    #pragma unroll
    for (int m = 0; m < 4; ++m)
        #pragma unroll
        for (int n = 0; n < 4; ++n)
            acc[m][n] = (f32x4)0.f;

    __syncthreads();    // W ready

    #pragma unroll
    for (int s = 0; s < 8; ++s) {
        bf16x8 a[4], b[4];
        #pragma unroll
        for (int m = 0; m < 4; ++m) {
            float4 u0 = *(const float4*)(aptr[m] + s * 32);
            float4 u1 = *(const float4*)(aptr[m] + s * 32 + 4);
            union { unsigned u[4]; bf16x8 v; } pk;
            pk.u[0] = cvt_pk_bf16(clampf(u0.x), clampf(u0.y));
            pk.u[1] = cvt_pk_bf16(clampf(u0.z), clampf(u0.w));
            pk.u[2] = cvt_pk_bf16(clampf(u1.x), clampf(u1.y));
            pk.u[3] = cvt_pk_bf16(clampf(u1.z), clampf(u1.w));
            a[m] = pk.v;
        }
        #pragma unroll
        for (int n = 0; n < 4; ++n) {
            int ncol  = wc * 64 + n * 16 + l15;
            int chunk = ncol * 32 + ((s * 4 + l4) ^ (ncol & 7));
            b[n] = *(const bf16x8*)&wlds[chunk];
        }
        #pragma unroll
        for (int m = 0; m < 4; ++m)
            #pragma unroll
            for (int n = 0; n < 4; ++n)
                acc[m][n] = __builtin_amdgcn_mfma_f32_16x16x32_bf16(
                    a[m], b[n], acc[m][n], 0, 0, 0);
    }

    // ---- epilogue A: acc -> LDS bf16 (chunk-swizzled), 256 x 512 B ----
    __syncthreads();
    {
        char* sl = (char*)wlds;
        #pragma unroll
        for (int m = 0; m < 4; ++m) {
            #pragma unroll
            for (int n = 0; n < 4; ++n) {
                int col2 = (wc * 64 + n * 16 + l15) * 2;
                #pragma unroll
                for (int r = 0; r < 4; ++r) {
                    int row = wr * 64 + m * 16 + l4 * 4 + r;
                    int off = row * 512 + (col2 ^ (((row >> 2) & 3) << 4));
                    *(unsigned short*)(sl + off) = (unsigned short)f2bf(clampf(acc[m][n][r]));
                }
            }
        }
    }
    __syncthreads();

    // ---- epilogue B: rowmax + quantize + int8 store ----
    {
        const uint4* sl4 = (const uint4*)wlds;
        const int row = t >> 2;         // 0..255
        const int qt  = t & 3;          // quarter of the row (64 feats)
        const int swz = (row >> 2) & 3;

        uint4 c[8];
        float mx = 0.f;
        #pragma unroll
        for (int j = 0; j < 8; ++j) {
            c[j] = sl4[row * 32 + ((qt * 8 + j) ^ swz)];
            const unsigned* cu = (const unsigned*)&c[j];
            #pragma unroll
            for (int q = 0; q < 4; ++q)
                mx = fmaxf(mx, fmaxf(fabsf(bflo(cu[q])), fabsf(bfhi(cu[q]))));
        }
        mx = fmaxf(mx, __shfl_xor(mx, 1));
        mx = fmaxf(mx, __shfl_xor(mx, 2));   // rowmax in all 4 quarter-threads

        const float inv = 127.f / fmaxf(mx, 1e-30f);
        const int grow = blockRow + row;
        if (grow < N_NODES) {
            unsigned p[16];
            #pragma unroll
            for (int j = 0; j < 8; ++j) {
                const unsigned* cu = (const unsigned*)&c[j];
                #pragma unroll
                for (int q = 0; q < 2; ++q) {
                    unsigned b0 = (unsigned)(int)rintf(bflo(cu[q*2+0]) * inv) + 128u;
                    unsigned b1 = (unsigned)(int)rintf(bfhi(cu[q*2+0]) * inv) + 128u;
                    unsigned b2 = (unsigned)(int)rintf(bflo(cu[q*2+1]) * inv) + 128u;
                    unsigned b3 = (unsigned)(int)rintf(bfhi(cu[q*2+1]) * inv) + 128u;
                    p[j*2+q] = b0 | (b1 << 8) | (b2 << 16) | (b3 << 24);
                }
            }
            uint4* dst = (uint4*)(sup8 + (size_t)grow * 64 + qt * 16);
            #pragma unroll
            for (int j = 0; j < 4; ++j)
                dst[j] = *(const uint4*)&p[j * 4];
            if (qt == 0) scales[grow] = mx * (1.f / 127.f);
        }
    }
}

// ---------------------------------------------------------------------------
// Kernel 3: out[r] = clip(relu(clip(sum val*support[c]) + bias)).
// One wave per row; lanes 0-31 even edges, 32-63 odd edges; 8 B (8 int8
// feats) per lane per edge. 8-edge main loop -> 4 gather chains in flight
// per half-wave. Dequant folded: acc += (val*scale)*ubyte, single -128*S
// correction at the end. fp32 accumulate.
// ---------------------------------------------------------------------------
#define FMAQ(g, vs)                                                       \
    S += (vs);                                                            \
    acc[0] += (vs) * (float)((g).x & 0xffu);                              \
    acc[1] += (vs) * (float)(((g).x >> 8) & 0xffu);                       \
    acc[2] += (vs) * (float)(((g).x >> 16) & 0xffu);                      \
    acc[3] += (vs) * (float)((g).x >> 24);                                \
    acc[4] += (vs) * (float)((g).y & 0xffu);                              \
    acc[5] += (vs) * (float)(((g).y >> 8) & 0xffu);                       \
    acc[6] += (vs) * (float)(((g).y >> 16) & 0xffu);                      \
    acc[7] += (vs) * (float)((g).y >> 24);

__global__ __launch_bounds__(256) void spmm_out(
    const unsigned* __restrict__ sup8, const float* __restrict__ scales,
    const int* __restrict__ row_ptr, const int* __restrict__ cols,
    const float* __restrict__ vals, const float* __restrict__ bias,
    float* __restrict__ out) {
    const int wid  = threadIdx.x >> 6;
    const int lane = threadIdx.x & 63;
    const int row  = blockIdx.x * 4 + wid;
    if (row >= N_NODES) return;

    const int e0   = row_ptr[row];
    const int e1   = row_ptr[row + 1];
    const int half = lane >> 5;       // 0: even edges, 1: odd edges
    const int c32  = lane & 31;       // 8B chunk within node row

    const uint2* sup2 = (const uint2*)sup8;
    float acc[8] = {0.f,0.f,0.f,0.f,0.f,0.f,0.f,0.f};
    float S = 0.f;

    int e = e0;
    for (; e + 8 <= e1; e += 8) {
        int   ea = e + half, eb = ea + 2, ec = ea + 4, ed = ea + 6;
        int   ca = cols[ea], cb = cols[eb], cc = cols[ec], cd = cols[ed];
        float va = vals[ea], vb = vals[eb], vc = vals[ec], vd = vals[ed];
        float vsa = va * scales[ca], vsb = vb * scales[cb];
        float vsc = vc * scales[cc], vsd = vd * scales[cd];
        uint2 ga = sup2[(size_t)ca * 32 + c32];
        uint2 gb = sup2[(size_t)cb * 32 + c32];
        uint2 gc = sup2[(size_t)cc * 32 + c32];
        uint2 gd = sup2[(size_t)cd * 32 + c32];
        FMAQ(ga, vsa); FMAQ(gb, vsb); FMAQ(gc, vsc); FMAQ(gd, vsd);
    }
    for (; e + 4 <= e1; e += 4) {
        int   ea = e + half, eb = ea + 2;
        int   ca = cols[ea], cb = cols[eb];
        float va = vals[ea], vb = vals[eb];
        float vsa = va * scales[ca], vsb = vb * scales[cb];
        uint2 ga = sup2[(size_t)ca * 32 + c32];
        uint2 gb = sup2[(size_t)cb * 32 + c32];
        FMAQ(ga, vsa); FMAQ(gb, vsb);
    }
    for (; e < e1; e += 2) {
        int   ea = e + half;
        bool  ok = ea < e1;
        int   ca = cols[ok ? ea : e];
        float va = ok ? vals[ea] : 0.f;
        float vsa = va * scales[ca];
        uint2 ga = sup2[(size_t)ca * 32 + c32];
        FMAQ(ga, vsa);
    }

    // offset-binary correction: true dequant = (b - 128) * scale
    S *= 128.f;
    #pragma unroll
    for (int j = 0; j < 8; ++j)
        acc[j] -= S;

    #pragma unroll
    for (int j = 0; j < 8; ++j)
        acc[j] += __shfl_xor(acc[j], 32);

    const float4 b4 = ((const float4*)bias)[c32 * 2 + half];
    f32x4 o;
    o.x = fminf(fmaxf(clampf(acc[half * 4 + 0]) + b4.x, 0.f), CLAMP_V);
    o.y = fminf(fmaxf(clampf(acc[half * 4 + 1]) + b4.y, 0.f), CLAMP_V);
    o.z = fminf(fmaxf(clampf(acc[half * 4 + 2]) + b4.z, 0.f), CLAMP_V);
    o.w = fminf(fmaxf(clampf(acc[half * 4 + 3]) + b4.w, 0.f), CLAMP_V);
    __builtin_nontemporal_store(o, (f32x4*)(out + (size_t)row * OUT_F + c32 * 8 + half * 4));
}

// ---------------------------------------------------------------------------
extern "C" void kernel_launch(void* const* d_in, const int* in_sizes, int n_in,
                              void* d_out, int out_size, void* d_ws, size_t ws_size,
                              hipStream_t stream) {
    const float* x        = (const float*)d_in[0];
    const int*   adj_rows = (const int*)d_in[1];
    const int*   adj_cols = (const int*)d_in[2];
    const float* adj_vals = (const float*)d_in[3];
    const float* weight   = (const float*)d_in[4];
    const float* bias     = (const float*)d_in[5];
    float*       out      = (float*)d_out;

    // ws: sup8 25.6MB | scales 400KB | row_ptr 400KB | wt 128KB  (~26.5 MB)
    char* ws = (char*)d_ws;
    unsigned*       sup8    = (unsigned*)ws;                        // 25,600,000
    float*          scales  = (float*)(ws + 25600000);              //    400,000
    int*            row_ptr = (int*)(ws + 26000000);                //    400,004
    unsigned short* wt      = (unsigned short*)(ws + 26400064);     //    131,072

    convert_w<<<256, 256, 0, stream>>>(weight, wt);
    build_row_ptr<<<(N_NODES + 1 + 255) / 256, 256, 0, stream>>>(adj_rows, row_ptr);
    gemm_mfma<<<(N_NODES + 255) / 256, 1024, 0, stream>>>(x, wt, sup8, scales);
    spmm_out<<<(N_NODES + 3) / 4, 256, 0, stream>>>(sup8, scales, row_ptr,
                                                    adj_cols, adj_vals, bias, out);
}

// Round 9
// 200.259 us; speedup vs baseline: 2.3311x; 1.0609x over previous
//
#include <hip/hip_runtime.h>

#define N_NODES 100000
#define N_EDGES 3200000
#define IN_F    256
#define OUT_F   256
#define CLAMP_V 10.0f

typedef __attribute__((ext_vector_type(8))) short bf16x8;
typedef __attribute__((ext_vector_type(4))) float f32x4;

__device__ __forceinline__ float clampf(float v) {
    return fminf(fmaxf(v, -CLAMP_V), CLAMP_V);
}
// RNE float -> bf16 (inputs clamped/finite)
__device__ __forceinline__ unsigned f2bf(float f) {
    unsigned u = __float_as_uint(f);
    u += 0x7fffu + ((u >> 16) & 1u);
    return u >> 16;
}
// packed 2x f32 -> 2x bf16 in one u32
__device__ __forceinline__ unsigned cvt_pk_bf16(float lo, float hi) {
    unsigned r;
    asm("v_cvt_pk_bf16_f32 %0, %1, %2" : "=v"(r) : "v"(lo), "v"(hi));
    return r;
}
__device__ __forceinline__ float bflo(unsigned w) { return __uint_as_float(w << 16); }
__device__ __forceinline__ float bfhi(unsigned w) { return __uint_as_float(w & 0xffff0000u); }

// ---------------------------------------------------------------------------
// Kernel 0: W fp32 [K][N] -> bf16, K-MAJOR chunk layout for coalesced
// global B-frag reads: element (k,n) at ushort idx (k>>3)*2048 + n*8 + (k&7).
// A wave's frag-load (16 consecutive ncol per quarter-wave) then reads
// 4 contiguous 256B runs -> fully coalesced from L2.
// ---------------------------------------------------------------------------
__global__ __launch_bounds__(256) void convert_w(
    const float* __restrict__ w, unsigned short* __restrict__ wt) {
    int i = blockIdx.x * 256 + threadIdx.x;   // 65536
    int k = i & 255, n = i >> 8;
    float v = w[(size_t)k * OUT_F + n];
    int dst = ((k >> 3) << 11) + (n << 3) + (k & 7);
    wt[dst] = (unsigned short)f2bf(v);
}

// ---------------------------------------------------------------------------
// Kernel 1: CSR row_ptr from sorted adj_rows (binary search per row).
// ---------------------------------------------------------------------------
__global__ __launch_bounds__(256) void build_row_ptr(
    const int* __restrict__ rows, int* __restrict__ row_ptr) {
    int r = blockIdx.x * blockDim.x + threadIdx.x;
    if (r > N_NODES) return;
    int lo = 0, hi = N_EDGES;
    while (lo < hi) {
        int mid = (lo + hi) >> 1;
        if (rows[mid] < r) lo = mid + 1; else hi = mid;
    }
    row_ptr[r] = lo;
}

// ---------------------------------------------------------------------------
// Kernel 2: fused GEMM + int8 quantization (NO W-in-LDS).
// 256 threads / 4 waves; tile 64 rows x 256 cols. A from global x (clamp+
// cvt in-reg), B-frags coalesced from global wt (L2-hot, 128 KB). Zero
// barriers in the K-loop; LDS = 32 KB epilogue transpose only -> 4-5
// blocks/CU, grid 1563 (fine-grain tail).
// Epilogue: acc -> LDS bf16 (swizzled) -> rowmax -> int8 store + scale.
// ---------------------------------------------------------------------------
__global__ __launch_bounds__(256) void gemm_mfma(
    const float* __restrict__ x, const unsigned short* __restrict__ wt,
    unsigned* __restrict__ sup8, float* __restrict__ scales) {
    __shared__ char sl[32768];      // 64 rows x 512 B

    const int t    = threadIdx.x;
    const int lane = t & 63;
    const int wc   = t >> 6;        // wave id = col slice 0..3
    const int l15  = lane & 15;
    const int l4   = lane >> 4;     // 0..3
    const int blockRow = blockIdx.x * 64;

    const float* aptr[4];
    #pragma unroll
    for (int m = 0; m < 4; ++m) {
        int r = blockRow + m * 16 + l15;
        aptr[m] = x + (size_t)(r < N_NODES ? r : N_NODES - 1) * IN_F + l4 * 8;
    }
    // B-frag base: ushort idx (s*4+l4)*2048 + ncol*8, ncol = wc*64+n*16+l15
    const unsigned short* bptr = wt + (l4 << 11) + ((wc * 64 + l15) << 3);

    f32x4 acc[4][4];
    #pragma unroll
    for (int m = 0; m < 4; ++m)
        #pragma unroll
        for (int n = 0; n < 4; ++n)
            acc[m][n] = (f32x4)0.f;

    #pragma unroll
    for (int s = 0; s < 8; ++s) {
        bf16x8 a[4], b[4];
        #pragma unroll
        for (int m = 0; m < 4; ++m) {
            float4 u0 = *(const float4*)(aptr[m] + s * 32);
            float4 u1 = *(const float4*)(aptr[m] + s * 32 + 4);
            union { unsigned u[4]; bf16x8 v; } pk;
            pk.u[0] = cvt_pk_bf16(clampf(u0.x), clampf(u0.y));
            pk.u[1] = cvt_pk_bf16(clampf(u0.z), clampf(u0.w));
            pk.u[2] = cvt_pk_bf16(clampf(u1.x), clampf(u1.y));
            pk.u[3] = cvt_pk_bf16(clampf(u1.z), clampf(u1.w));
            a[m] = pk.v;
        }
        #pragma unroll
        for (int n = 0; n < 4; ++n)
            b[n] = *(const bf16x8*)(bptr + (s << 13) + (n << 7));
        #pragma unroll
        for (int m = 0; m < 4; ++m)
            #pragma unroll
            for (int n = 0; n < 4; ++n)
                acc[m][n] = __builtin_amdgcn_mfma_f32_16x16x32_bf16(
                    a[m], b[n], acc[m][n], 0, 0, 0);
    }

    // ---- epilogue A: acc -> LDS bf16 (chunk-swizzled), 64 x 512 B ----
    #pragma unroll
    for (int m = 0; m < 4; ++m) {
        #pragma unroll
        for (int n = 0; n < 4; ++n) {
            int col2 = (wc * 64 + n * 16 + l15) * 2;
            #pragma unroll
            for (int r = 0; r < 4; ++r) {
                int row = m * 16 + l4 * 4 + r;
                int off = row * 512 + (col2 ^ (((row >> 2) & 3) << 4));
                *(unsigned short*)(sl + off) = (unsigned short)f2bf(clampf(acc[m][n][r]));
            }
        }
    }
    __syncthreads();

    // ---- epilogue B: rowmax + quantize + int8 store ----
    {
        const uint4* sl4 = (const uint4*)sl;
        const int row = t >> 2;         // 0..63
        const int qt  = t & 3;          // quarter of the row (64 feats)
        const int swz = (row >> 2) & 3;

        uint4 c[8];
        float mx = 0.f;
        #pragma unroll
        for (int j = 0; j < 8; ++j) {
            c[j] = sl4[row * 32 + ((qt * 8 + j) ^ swz)];
            const unsigned* cu = (const unsigned*)&c[j];
            #pragma unroll
            for (int q = 0; q < 4; ++q)
                mx = fmaxf(mx, fmaxf(fabsf(bflo(cu[q])), fabsf(bfhi(cu[q]))));
        }
        mx = fmaxf(mx, __shfl_xor(mx, 1));
        mx = fmaxf(mx, __shfl_xor(mx, 2));   // rowmax in all 4 quarter-threads

        const float inv = 127.f / fmaxf(mx, 1e-30f);
        const int grow = blockRow + row;
        if (grow < N_NODES) {
            unsigned p[16];
            #pragma unroll
            for (int j = 0; j < 8; ++j) {
                const unsigned* cu = (const unsigned*)&c[j];
                #pragma unroll
                for (int q = 0; q < 2; ++q) {
                    unsigned b0 = (unsigned)(int)rintf(bflo(cu[q*2+0]) * inv) + 128u;
                    unsigned b1 = (unsigned)(int)rintf(bfhi(cu[q*2+0]) * inv) + 128u;
                    unsigned b2 = (unsigned)(int)rintf(bflo(cu[q*2+1]) * inv) + 128u;
                    unsigned b3 = (unsigned)(int)rintf(bfhi(cu[q*2+1]) * inv) + 128u;
                    p[j*2+q] = b0 | (b1 << 8) | (b2 << 16) | (b3 << 24);
                }
            }
            uint4* dst = (uint4*)(sup8 + (size_t)grow * 64 + qt * 16);
            #pragma unroll
            for (int j = 0; j < 4; ++j)
                dst[j] = *(const uint4*)&p[j * 4];
            if (qt == 0) scales[grow] = mx * (1.f / 127.f);
        }
    }
}

// ---------------------------------------------------------------------------
// Kernel 3: out[r] = clip(relu(clip(sum val*support[c]) + bias)).
// One wave per row; lanes 0-31 even edges, 32-63 odd edges; 8 B (8 int8
// feats) per lane per edge; 8-edge main loop (4 gather chains in flight).
// Dequant folded: acc += (val*scale)*ubyte, single -128*S correction.
// ---------------------------------------------------------------------------
#define FMAQ(g, vs)                                                       \
    S += (vs);                                                            \
    acc[0] += (vs) * (float)((g).x & 0xffu);                              \
    acc[1] += (vs) * (float)(((g).x >> 8) & 0xffu);                       \
    acc[2] += (vs) * (float)(((g).x >> 16) & 0xffu);                      \
    acc[3] += (vs) * (float)((g).x >> 24);                                \
    acc[4] += (vs) * (float)((g).y & 0xffu);                              \
    acc[5] += (vs) * (float)(((g).y >> 8) & 0xffu);                       \
    acc[6] += (vs) * (float)(((g).y >> 16) & 0xffu);                      \
    acc[7] += (vs) * (float)((g).y >> 24);

__global__ __launch_bounds__(256) void spmm_out(
    const unsigned* __restrict__ sup8, const float* __restrict__ scales,
    const int* __restrict__ row_ptr, const int* __restrict__ cols,
    const float* __restrict__ vals, const float* __restrict__ bias,
    float* __restrict__ out) {
    const int wid  = threadIdx.x >> 6;
    const int lane = threadIdx.x & 63;
    const int row  = blockIdx.x * 4 + wid;
    if (row >= N_NODES) return;

    const int e0   = row_ptr[row];
    const int e1   = row_ptr[row + 1];
    const int half = lane >> 5;       // 0: even edges, 1: odd edges
    const int c32  = lane & 31;       // 8B chunk within node row

    const uint2* sup2 = (const uint2*)sup8;
    float acc[8] = {0.f,0.f,0.f,0.f,0.f,0.f,0.f,0.f};
    float S = 0.f;

    int e = e0;
    for (; e + 8 <= e1; e += 8) {
        int   ea = e + half, eb = ea + 2, ec = ea + 4, ed = ea + 6;
        int   ca = cols[ea], cb = cols[eb], cc = cols[ec], cd = cols[ed];
        float va = vals[ea], vb = vals[eb], vc = vals[ec], vd = vals[ed];
        float vsa = va * scales[ca], vsb = vb * scales[cb];
        float vsc = vc * scales[cc], vsd = vd * scales[cd];
        uint2 ga = sup2[(size_t)ca * 32 + c32];
        uint2 gb = sup2[(size_t)cb * 32 + c32];
        uint2 gc = sup2[(size_t)cc * 32 + c32];
        uint2 gd = sup2[(size_t)cd * 32 + c32];
        FMAQ(ga, vsa); FMAQ(gb, vsb); FMAQ(gc, vsc); FMAQ(gd, vsd);
    }
    for (; e + 4 <= e1; e += 4) {
        int   ea = e + half, eb = ea + 2;
        int   ca = cols[ea], cb = cols[eb];
        float va = vals[ea], vb = vals[eb];
        float vsa = va * scales[ca], vsb = vb * scales[cb];
        uint2 ga = sup2[(size_t)ca * 32 + c32];
        uint2 gb = sup2[(size_t)cb * 32 + c32];
        FMAQ(ga, vsa); FMAQ(gb, vsb);
    }
    for (; e < e1; e += 2) {
        int   ea = e + half;
        bool  ok = ea < e1;
        int   ca = cols[ok ? ea : e];
        float va = ok ? vals[ea] : 0.f;
        float vsa = va * scales[ca];
        uint2 ga = sup2[(size_t)ca * 32 + c32];
        FMAQ(ga, vsa);
    }

    // offset-binary correction: true dequant = (b - 128) * scale
    S *= 128.f;
    #pragma unroll
    for (int j = 0; j < 8; ++j)
        acc[j] -= S;

    #pragma unroll
    for (int j = 0; j < 8; ++j)
        acc[j] += __shfl_xor(acc[j], 32);

    const float4 b4 = ((const float4*)bias)[c32 * 2 + half];
    f32x4 o;
    o.x = fminf(fmaxf(clampf(acc[half * 4 + 0]) + b4.x, 0.f), CLAMP_V);
    o.y = fminf(fmaxf(clampf(acc[half * 4 + 1]) + b4.y, 0.f), CLAMP_V);
    o.z = fminf(fmaxf(clampf(acc[half * 4 + 2]) + b4.z, 0.f), CLAMP_V);
    o.w = fminf(fmaxf(clampf(acc[half * 4 + 3]) + b4.w, 0.f), CLAMP_V);
    __builtin_nontemporal_store(o, (f32x4*)(out + (size_t)row * OUT_F + c32 * 8 + half * 4));
}

// ---------------------------------------------------------------------------
extern "C" void kernel_launch(void* const* d_in, const int* in_sizes, int n_in,
                              void* d_out, int out_size, void* d_ws, size_t ws_size,
                              hipStream_t stream) {
    const float* x        = (const float*)d_in[0];
    const int*   adj_rows = (const int*)d_in[1];
    const int*   adj_cols = (const int*)d_in[2];
    const float* adj_vals = (const float*)d_in[3];
    const float* weight   = (const float*)d_in[4];
    const float* bias     = (const float*)d_in[5];
    float*       out      = (float*)d_out;

    // ws: sup8 25.6MB | scales 400KB | row_ptr 400KB | wt 128KB  (~26.5 MB)
    char* ws = (char*)d_ws;
    unsigned*       sup8    = (unsigned*)ws;                        // 25,600,000
    float*          scales  = (float*)(ws + 25600000);              //    400,000
    int*            row_ptr = (int*)(ws + 26000000);                //    400,004
    unsigned short* wt      = (unsigned short*)(ws + 26400064);     //    131,072

    convert_w<<<256, 256, 0, stream>>>(weight, wt);
    build_row_ptr<<<(N_NODES + 1 + 255) / 256, 256, 0, stream>>>(adj_rows, row_ptr);
    gemm_mfma<<<(N_NODES + 63) / 64, 256, 0, stream>>>(x, wt, sup8, scales);
    spmm_out<<<(N_NODES + 3) / 4, 256, 0, stream>>>(sup8, scales, row_ptr,
                                                    adj_cols, adj_vals, bias, out);
}

// Round 10
// 174.200 us; speedup vs baseline: 2.6798x; 1.1496x over previous
//
#include <hip/hip_runtime.h>

#define N_NODES 100000
#define N_EDGES 3200000
#define IN_F    256
#define OUT_F   256
#define CLAMP_V 10.0f

typedef __attribute__((ext_vector_type(8))) short bf16x8;
typedef __attribute__((ext_vector_type(4))) float f32x4;

__device__ __forceinline__ float clampf(float v) {
    return fminf(fmaxf(v, -CLAMP_V), CLAMP_V);
}
// RNE float -> bf16 (inputs clamped/finite)
__device__ __forceinline__ unsigned f2bf(float f) {
    unsigned u = __float_as_uint(f);
    u += 0x7fffu + ((u >> 16) & 1u);
    return u >> 16;
}
// packed 2x f32 -> 2x bf16 in one u32
__device__ __forceinline__ unsigned cvt_pk_bf16(float lo, float hi) {
    unsigned r;
    asm("v_cvt_pk_bf16_f32 %0, %1, %2" : "=v"(r) : "v"(lo), "v"(hi));
    return r;
}
__device__ __forceinline__ float bflo(unsigned w) { return __uint_as_float(w << 16); }
__device__ __forceinline__ float bfhi(unsigned w) { return __uint_as_float(w & 0xffff0000u); }

// ---------------------------------------------------------------------------
// Kernel 0 (merged): blocks 0..255 convert W -> bf16 k-major
//   element (k,n) at ushort idx (k>>3)*2048 + n*8 + (k&7);
// blocks 256.. build CSR row_ptr from sorted adj_rows (binary search).
// ---------------------------------------------------------------------------
__global__ __launch_bounds__(256) void prep(
    const float* __restrict__ w, unsigned short* __restrict__ wt,
    const int* __restrict__ rows, int* __restrict__ row_ptr) {
    const int bid = blockIdx.x;
    if (bid < 256) {
        int i = bid * 256 + threadIdx.x;   // 65536
        int k = i & 255, n = i >> 8;
        float v = w[(size_t)k * OUT_F + n];
        int dst = ((k >> 3) << 11) + (n << 3) + (k & 7);
        wt[dst] = (unsigned short)f2bf(v);
    } else {
        int r = (bid - 256) * 256 + threadIdx.x;
        if (r > N_NODES) return;
        int lo = 0, hi = N_EDGES;
        while (lo < hi) {
            int mid = (lo + hi) >> 1;
            if (rows[mid] < r) lo = mid + 1; else hi = mid;
        }
        row_ptr[r] = lo;
    }
}

// ---------------------------------------------------------------------------
// Kernel 1: fused GEMM + int8 quantization, LDS-staged x streaming.
// 256 threads / 4 waves; tile 64 rows x 256 cols, BK=64, double-buffered
// 16 KB x-tiles. Staging: thread t covers (row=t>>2, 64B quarter qt=t&3);
// XOR swizzle chunk^(row&15) on BOTH ds_write and ds_read (16B granular,
// even bank distribution). Next-step loads issue into regs while current
// step computes from LDS -> streaming decoupled from VGPR budget.
// B-frags coalesced from global wt (L2-hot). 1 barrier per K-step.
// Epilogue: acc -> LDS bf16 (swizzled) -> rowmax -> int8 + scale.
// ---------------------------------------------------------------------------
__global__ __launch_bounds__(256) void gemm_mfma(
    const float* __restrict__ x, const unsigned short* __restrict__ wt,
    unsigned* __restrict__ sup8, float* __restrict__ scales) {
    __shared__ char lds[32768];     // 2 x 16 KB staging; reused by epilogue

    const int t    = threadIdx.x;
    const int lane = t & 63;
    const int wc   = t >> 6;        // wave id = col slice 0..3
    const int l15  = lane & 15;
    const int l4   = lane >> 4;     // 0..3
    const int blockRow = blockIdx.x * 64;

    // ---- staging mapping: thread covers 64 B of one row per K-step ----
    const int srow = t >> 2;        // 0..63
    const int sqt  = t & 3;         // 64B quarter of the 256B row-step slice
    int sgrow = blockRow + srow; if (sgrow >= N_NODES) sgrow = N_NODES - 1;
    const float* sbase = x + (size_t)sgrow * IN_F + sqt * 16;
    int woff[4];
    #pragma unroll
    for (int j = 0; j < 4; ++j) {
        int chunk = sqt * 4 + j;
        woff[j] = srow * 256 + ((chunk ^ (srow & 15)) << 4);
    }

    f32x4 st[4];
    #pragma unroll
    for (int j = 0; j < 4; ++j)
        st[j] = *(const f32x4*)(sbase + j * 4);      // K-step 0

    f32x4 acc[4][4];
    #pragma unroll
    for (int m = 0; m < 4; ++m)
        #pragma unroll
        for (int n = 0; n < 4; ++n)
            acc[m][n] = (f32x4)0.f;

    #pragma unroll
    for (int s = 0; s < 4; ++s) {
        char* buf = lds + (s & 1) * 16384;
        #pragma unroll
        for (int j = 0; j < 4; ++j)
            *(f32x4*)(buf + woff[j]) = st[j];
        if (s < 3) {                                  // prefetch next K-step
            const float* nb = sbase + (s + 1) * 64;
            #pragma unroll
            for (int j = 0; j < 4; ++j)
                st[j] = *(const f32x4*)(nb + j * 4);
        }
        __syncthreads();    // staging visible; prior-step reads of this buf
                            // were fenced by the previous step's barrier

        #pragma unroll
        for (int kk = 0; kk < 2; ++kk) {
            bf16x8 a[4], b[4];
            #pragma unroll
            for (int m = 0; m < 4; ++m) {
                const int row = m * 16 + l15;
                const int c0 = (kk * 8 + l4 * 2 + 0) ^ l15;
                const int c1 = (kk * 8 + l4 * 2 + 1) ^ l15;
                f32x4 u0 = *(const f32x4*)(buf + row * 256 + (c0 << 4));
                f32x4 u1 = *(const f32x4*)(buf + row * 256 + (c1 << 4));
                union { unsigned u[4]; bf16x8 v; } pk;
                pk.u[0] = cvt_pk_bf16(clampf(u0[0]), clampf(u0[1]));
                pk.u[1] = cvt_pk_bf16(clampf(u0[2]), clampf(u0[3]));
                pk.u[2] = cvt_pk_bf16(clampf(u1[0]), clampf(u1[1]));
                pk.u[3] = cvt_pk_bf16(clampf(u1[2]), clampf(u1[3]));
                a[m] = pk.v;
            }
            const int kg = s * 8 + kk * 4 + l4;       // global k>>3
            #pragma unroll
            for (int n = 0; n < 4; ++n)
                b[n] = *(const bf16x8*)(wt + (kg << 11) + ((wc * 64 + n * 16 + l15) << 3));
            #pragma unroll
            for (int m = 0; m < 4; ++m)
                #pragma unroll
                for (int n = 0; n < 4; ++n)
                    acc[m][n] = __builtin_amdgcn_mfma_f32_16x16x32_bf16(
                        a[m], b[n], acc[m][n], 0, 0, 0);
        }
    }
    __syncthreads();    // all K-loop LDS reads done before epilogue reuse

    // ---- epilogue A: acc -> LDS bf16 (chunk-swizzled), 64 x 512 B ----
    {
        char* sl = lds;
        #pragma unroll
        for (int m = 0; m < 4; ++m) {
            #pragma unroll
            for (int n = 0; n < 4; ++n) {
                int col2 = (wc * 64 + n * 16 + l15) * 2;
                #pragma unroll
                for (int r = 0; r < 4; ++r) {
                    int row = m * 16 + l4 * 4 + r;
                    int off = row * 512 + (col2 ^ (((row >> 2) & 3) << 4));
                    *(unsigned short*)(sl + off) = (unsigned short)f2bf(clampf(acc[m][n][r]));
                }
            }
        }
    }
    __syncthreads();

    // ---- epilogue B: rowmax + quantize + int8 store ----
    {
        const uint4* sl4 = (const uint4*)lds;
        const int row = t >> 2;         // 0..63
        const int qt  = t & 3;          // quarter of the row (64 feats)
        const int swz = (row >> 2) & 3;

        uint4 c[8];
        float mx = 0.f;
        #pragma unroll
        for (int j = 0; j < 8; ++j) {
            c[j] = sl4[row * 32 + ((qt * 8 + j) ^ swz)];
            const unsigned* cu = (const unsigned*)&c[j];
            #pragma unroll
            for (int q = 0; q < 4; ++q)
                mx = fmaxf(mx, fmaxf(fabsf(bflo(cu[q])), fabsf(bfhi(cu[q]))));
        }
        mx = fmaxf(mx, __shfl_xor(mx, 1));
        mx = fmaxf(mx, __shfl_xor(mx, 2));   // rowmax in all 4 quarter-threads

        const float inv = 127.f / fmaxf(mx, 1e-30f);
        const int grow = blockRow + row;
        if (grow < N_NODES) {
            unsigned p[16];
            #pragma unroll
            for (int j = 0; j < 8; ++j) {
                const unsigned* cu = (const unsigned*)&c[j];
                #pragma unroll
                for (int q = 0; q < 2; ++q) {
                    unsigned b0 = (unsigned)(int)rintf(bflo(cu[q*2+0]) * inv) + 128u;
                    unsigned b1 = (unsigned)(int)rintf(bfhi(cu[q*2+0]) * inv) + 128u;
                    unsigned b2 = (unsigned)(int)rintf(bflo(cu[q*2+1]) * inv) + 128u;
                    unsigned b3 = (unsigned)(int)rintf(bfhi(cu[q*2+1]) * inv) + 128u;
                    p[j*2+q] = b0 | (b1 << 8) | (b2 << 16) | (b3 << 24);
                }
            }
            uint4* dst = (uint4*)(sup8 + (size_t)grow * 64 + qt * 16);
            #pragma unroll
            for (int j = 0; j < 4; ++j)
                dst[j] = *(const uint4*)&p[j * 4];
            if (qt == 0) scales[grow] = mx * (1.f / 127.f);
        }
    }
}

// ---------------------------------------------------------------------------
// Kernel 2: out[r] = clip(relu(clip(sum val*support[c]) + bias)).
// One wave per row; lanes 0-31 even edges, 32-63 odd edges; 8 B (8 int8
// feats) per lane per edge; 8-edge main loop (4 gather chains in flight).
// Dequant folded: acc += (val*scale)*ubyte, single -128*S correction.
// ---------------------------------------------------------------------------
#define FMAQ(g, vs)                                                       \
    S += (vs);                                                            \
    acc[0] += (vs) * (float)((g).x & 0xffu);                              \
    acc[1] += (vs) * (float)(((g).x >> 8) & 0xffu);                       \
    acc[2] += (vs) * (float)(((g).x >> 16) & 0xffu);                      \
    acc[3] += (vs) * (float)((g).x >> 24);                                \
    acc[4] += (vs) * (float)((g).y & 0xffu);                              \
    acc[5] += (vs) * (float)(((g).y >> 8) & 0xffu);                       \
    acc[6] += (vs) * (float)(((g).y >> 16) & 0xffu);                      \
    acc[7] += (vs) * (float)((g).y >> 24);

__global__ __launch_bounds__(256) void spmm_out(
    const unsigned* __restrict__ sup8, const float* __restrict__ scales,
    const int* __restrict__ row_ptr, const int* __restrict__ cols,
    const float* __restrict__ vals, const float* __restrict__ bias,
    float* __restrict__ out) {
    const int wid  = threadIdx.x >> 6;
    const int lane = threadIdx.x & 63;
    const int row  = blockIdx.x * 4 + wid;
    if (row >= N_NODES) return;

    const int e0   = row_ptr[row];
    const int e1   = row_ptr[row + 1];
    const int half = lane >> 5;       // 0: even edges, 1: odd edges
    const int c32  = lane & 31;       // 8B chunk within node row

    const uint2* sup2 = (const uint2*)sup8;
    float acc[8] = {0.f,0.f,0.f,0.f,0.f,0.f,0.f,0.f};
    float S = 0.f;

    int e = e0;
    for (; e + 8 <= e1; e += 8) {
        int   ea = e + half, eb = ea + 2, ec = ea + 4, ed = ea + 6;
        int   ca = cols[ea], cb = cols[eb], cc = cols[ec], cd = cols[ed];
        float va = vals[ea], vb = vals[eb], vc = vals[ec], vd = vals[ed];
        float vsa = va * scales[ca], vsb = vb * scales[cb];
        float vsc = vc * scales[cc], vsd = vd * scales[cd];
        uint2 ga = sup2[(size_t)ca * 32 + c32];
        uint2 gb = sup2[(size_t)cb * 32 + c32];
        uint2 gc = sup2[(size_t)cc * 32 + c32];
        uint2 gd = sup2[(size_t)cd * 32 + c32];
        FMAQ(ga, vsa); FMAQ(gb, vsb); FMAQ(gc, vsc); FMAQ(gd, vsd);
    }
    for (; e + 4 <= e1; e += 4) {
        int   ea = e + half, eb = ea + 2;
        int   ca = cols[ea], cb = cols[eb];
        float va = vals[ea], vb = vals[eb];
        float vsa = va * scales[ca], vsb = vb * scales[cb];
        uint2 ga = sup2[(size_t)ca * 32 + c32];
        uint2 gb = sup2[(size_t)cb * 32 + c32];
        FMAQ(ga, vsa); FMAQ(gb, vsb);
    }
    for (; e < e1; e += 2) {
        int   ea = e + half;
        bool  ok = ea < e1;
        int   ca = cols[ok ? ea : e];
        float va = ok ? vals[ea] : 0.f;
        float vsa = va * scales[ca];
        uint2 ga = sup2[(size_t)ca * 32 + c32];
        FMAQ(ga, vsa);
    }

    // offset-binary correction: true dequant = (b - 128) * scale
    S *= 128.f;
    #pragma unroll
    for (int j = 0; j < 8; ++j)
        acc[j] -= S;

    #pragma unroll
    for (int j = 0; j < 8; ++j)
        acc[j] += __shfl_xor(acc[j], 32);

    const float4 b4 = ((const float4*)bias)[c32 * 2 + half];
    f32x4 o;
    o.x = fminf(fmaxf(clampf(acc[half * 4 + 0]) + b4.x, 0.f), CLAMP_V);
    o.y = fminf(fmaxf(clampf(acc[half * 4 + 1]) + b4.y, 0.f), CLAMP_V);
    o.z = fminf(fmaxf(clampf(acc[half * 4 + 2]) + b4.z, 0.f), CLAMP_V);
    o.w = fminf(fmaxf(clampf(acc[half * 4 + 3]) + b4.w, 0.f), CLAMP_V);
    __builtin_nontemporal_store(o, (f32x4*)(out + (size_t)row * OUT_F + c32 * 8 + half * 4));
}

// ---------------------------------------------------------------------------
extern "C" void kernel_launch(void* const* d_in, const int* in_sizes, int n_in,
                              void* d_out, int out_size, void* d_ws, size_t ws_size,
                              hipStream_t stream) {
    const float* x        = (const float*)d_in[0];
    const int*   adj_rows = (const int*)d_in[1];
    const int*   adj_cols = (const int*)d_in[2];
    const float* adj_vals = (const float*)d_in[3];
    const float* weight   = (const float*)d_in[4];
    const float* bias     = (const float*)d_in[5];
    float*       out      = (float*)d_out;

    // ws: sup8 25.6MB | scales 400KB | row_ptr 400KB | wt 128KB  (~26.5 MB)
    char* ws = (char*)d_ws;
    unsigned*       sup8    = (unsigned*)ws;                        // 25,600,000
    float*          scales  = (float*)(ws + 25600000);              //    400,000
    int*            row_ptr = (int*)(ws + 26000000);                //    400,004
    unsigned short* wt      = (unsigned short*)(ws + 26400064);     //    131,072

    const int rp_blocks = (N_NODES + 1 + 255) / 256;                // 392
    prep<<<256 + rp_blocks, 256, 0, stream>>>(weight, wt, adj_rows, row_ptr);
    gemm_mfma<<<(N_NODES + 63) / 64, 256, 0, stream>>>(x, wt, sup8, scales);
    spmm_out<<<(N_NODES + 3) / 4, 256, 0, stream>>>(sup8, scales, row_ptr,
                                                    adj_cols, adj_vals, bias, out);
}